// Round 15
// baseline (862.030 us; speedup 1.0000x reference)
//
#include <hip/hip_runtime.h>

// Semi-CRF log-partition. B=4, T=512, L=96, W=63.
// v15: NOTHING runs at full rate except the 2-wave core (stage-rate law:
// r = slowest full-rate stage; v8/v11/v12/v14 all bound at 1.3-1.9us by some
// full-rate helper stage).
//  - finalizer: waves 0,1 = CORE halves (d=1, bf16-ring matvec, 2-term merge);
//    waves 2-5 = REST parity x half (stride 2): 8 chain ends + z. No other
//    stages. Core publishes axp FIRST (fire-and-forget) to shorten d2 path.
//  - ALL d>=2 via relay chains (d=2..63, parity-split, 8 chains/parity,
//    ends d=2..9). REST issues ends-2,3 loads fresh at iteration top (latency
//    hides under z + 6 prefetched validations); ends>=4 stride-2 prefetched.
// Handoffs: 8B relaxed agent atomics (axp NaN sentinel, chain tag in low 8
// mantissa bits of v); LDS flags relaxed + lgkmcnt(0) only. VGPR<=128.

#define Tn 512
#define Ln 96
#define HL 48
#define LSQ (Ln * Ln)
#define Wn 63
#define KCH 8
#define NROLE 32  // 1 finalizer + 31 relay roles (4 pair-units each) per batch
#define NEGINF (-1e30f)
#define SENT 0x7FC00000u

#define AGENT __HIP_MEMORY_SCOPE_AGENT
#define WG __HIP_MEMORY_SCOPE_WORKGROUP
#define RLX __ATOMIC_RELAXED
#define LDSF() asm volatile("s_waitcnt lgkmcnt(0)" ::: "memory")
#define CBAR() asm volatile("" ::: "memory")
#define SIDX(b, i, t) ((((size_t)(b) * Tn + (i)) * Tn + (t)) * Ln)

typedef unsigned long long u64;
typedef unsigned int u32;
typedef unsigned short u16;

__device__ __forceinline__ float wsumred(float v) {
#pragma unroll
  for (int m = 32; m >= 1; m >>= 1) v += __shfl_xor(v, m, 64);
  return v;
}
__device__ __forceinline__ u64 pack2(float lo, float hi) {
  return (u64)__float_as_uint(lo) | ((u64)__float_as_uint(hi) << 32);
}
__device__ __forceinline__ u16 tobf16(float x) {
  return (u16)((__float_as_uint(x) + 0x8000u) >> 16);
}
__device__ __forceinline__ float wavemax48(float v) {
  int x;
  x = __builtin_amdgcn_update_dpp(__float_as_int(v), __float_as_int(v), 0xB1,
                                  0xF, 0xF, false);
  v = fmaxf(v, __int_as_float(x));
  x = __builtin_amdgcn_update_dpp(__float_as_int(v), __float_as_int(v), 0x4E,
                                  0xF, 0xF, false);
  v = fmaxf(v, __int_as_float(x));
  x = __builtin_amdgcn_update_dpp(__float_as_int(v), __float_as_int(v), 0x141,
                                  0xF, 0xF, false);
  v = fmaxf(v, __int_as_float(x));
  x = __builtin_amdgcn_update_dpp(__float_as_int(v), __float_as_int(v), 0x140,
                                  0xF, 0xF, false);
  v = fmaxf(v, __int_as_float(x));
  float r0 = __int_as_float(__builtin_amdgcn_readlane(__float_as_int(v), 0));
  float r1 = __int_as_float(__builtin_amdgcn_readlane(__float_as_int(v), 16));
  float r2 = __int_as_float(__builtin_amdgcn_readlane(__float_as_int(v), 32));
  float r3 = __int_as_float(__builtin_amdgcn_readlane(__float_as_int(v), 48));
  return fmaxf(fmaxf(r0, r1), fmaxf(r2, r3));
}
__device__ __forceinline__ float comb(float Slo, float Shi, float C0, float C1,
                                      float wseg) {
  const float Cm = fmaxf(C0, C1);
  return Cm + wseg + __logf(__expf(C0 - Cm) * Slo + __expf(C1 - Cm) * Shi);
}

// f32 matvec (relays): 24 ds_read_b128
#define MV1(SRC, RR, SLO, SHI)                                       \
  float SLO, SHI;                                                    \
  {                                                                  \
    const float4* A4 = (const float4*)(SRC);                         \
    float a0 = 0, a1 = 0, a2 = 0, a3 = 0;                            \
    _Pragma("unroll") for (int q = 0; q < 12; ++q) {                 \
      float4 a = A4[q];                                              \
      a0 = fmaf(a.x, RR[4 * q + 0], a0);                             \
      a1 = fmaf(a.y, RR[4 * q + 1], a1);                             \
      a2 = fmaf(a.z, RR[4 * q + 2], a2);                             \
      a3 = fmaf(a.w, RR[4 * q + 3], a3);                             \
    }                                                                \
    SLO = (a0 + a1) + (a2 + a3);                                     \
    float b0 = 0, b1 = 0, b2 = 0, b3 = 0;                            \
    _Pragma("unroll") for (int q = 12; q < 24; ++q) {                \
      float4 a = A4[q];                                              \
      b0 = fmaf(a.x, RR[4 * q + 0], b0);                             \
      b1 = fmaf(a.y, RR[4 * q + 1], b1);                             \
      b2 = fmaf(a.z, RR[4 * q + 2], b2);                             \
      b3 = fmaf(a.w, RR[4 * q + 3], b3);                             \
    }                                                                \
    SHI = (b0 + b1) + (b2 + b3);                                     \
  }

// bf16 matvec (core): 12 ds_read_b128, shift/and unpack
#define MVB(SRC, RR, SLO, SHI)                                               \
  float SLO, SHI;                                                            \
  {                                                                          \
    const uint4* A4 = (const uint4*)(SRC);                                   \
    float a0 = 0, a1 = 0, a2 = 0, a3 = 0;                                    \
    _Pragma("unroll") for (int q = 0; q < 6; ++q) {                          \
      uint4 a = A4[q];                                                       \
      a0 = fmaf(__uint_as_float(a.x << 16), RR[8 * q + 0], a0);              \
      a1 = fmaf(__uint_as_float(a.x & 0xFFFF0000u), RR[8 * q + 1], a1);      \
      a2 = fmaf(__uint_as_float(a.y << 16), RR[8 * q + 2], a2);              \
      a3 = fmaf(__uint_as_float(a.y & 0xFFFF0000u), RR[8 * q + 3], a3);      \
      a0 = fmaf(__uint_as_float(a.z << 16), RR[8 * q + 4], a0);              \
      a1 = fmaf(__uint_as_float(a.z & 0xFFFF0000u), RR[8 * q + 5], a1);      \
      a2 = fmaf(__uint_as_float(a.w << 16), RR[8 * q + 6], a2);              \
      a3 = fmaf(__uint_as_float(a.w & 0xFFFF0000u), RR[8 * q + 7], a3);      \
    }                                                                        \
    SLO = (a0 + a1) + (a2 + a3);                                             \
    float b0 = 0, b1 = 0, b2 = 0, b3 = 0;                                    \
    _Pragma("unroll") for (int q = 6; q < 12; ++q) {                         \
      uint4 a = A4[q];                                                       \
      b0 = fmaf(__uint_as_float(a.x << 16), RR[8 * q + 0], b0);              \
      b1 = fmaf(__uint_as_float(a.x & 0xFFFF0000u), RR[8 * q + 1], b1);      \
      b2 = fmaf(__uint_as_float(a.y << 16), RR[8 * q + 2], b2);              \
      b3 = fmaf(__uint_as_float(a.y & 0xFFFF0000u), RR[8 * q + 3], b3);      \
      b0 = fmaf(__uint_as_float(a.z << 16), RR[8 * q + 4], b0);              \
      b1 = fmaf(__uint_as_float(a.z & 0xFFFF0000u), RR[8 * q + 5], b1);      \
      b2 = fmaf(__uint_as_float(a.w << 16), RR[8 * q + 6], b2);              \
      b3 = fmaf(__uint_as_float(a.w & 0xFFFF0000u), RR[8 * q + 7], b3);      \
    }                                                                        \
    SHI = (b0 + b1) + (b2 + b3);                                             \
  }

__global__ void init_ws(u64* ws) {
  const size_t n1 = (size_t)4 * Tn * Ln;
  const size_t n = n1 * 9;  // axp + 8 chains
  for (size_t i = (size_t)blockIdx.x * blockDim.x + threadIdx.x; i < n;
       i += (size_t)gridDim.x * blockDim.x)
    ws[i] = (i < n1) ? (((u64)SENT) << 32) : 0ull;
}

__global__ __launch_bounds__(512, 1) void semicrf(
    const float* __restrict__ seg, const float* __restrict__ tr,
    float* __restrict__ out, u64* axp, u64* acc) {
  const int b = blockIdx.x / NROLE;
  const int role = blockIdx.x % NROLE;
  const int tid = threadIdx.x;

  __shared__ __align__(16) float E[LSQ];           // exp(trans) 36 KB
  __shared__ __align__(16) u16 AlbRh[8][Ln];       // bf16 alpha ring
  __shared__ float CRng[8][2];                     // per-half C ring
  __shared__ float RESTm[4][Ln];                   // chains+z merge (m)
  __shared__ float RESTv[4][Ln];                   // chains+z merge (v)
  __shared__ __align__(16) float Alb_s[4][2][Ln];  // relay staging (dbuf)
  __shared__ float CstS[4][2][2];
  __shared__ float redbuf[2];
  __shared__ int seqA[2], rq[2][2], rfl[2];
  __shared__ int stg[4][2];

  if (tid < 2) { seqA[tid] = -1; rfl[tid] = -1; }
  if (tid < 4) rq[tid >> 1][tid & 1] = -1;
  if (tid < 8) stg[tid >> 1][tid & 1] = -1;
  for (int i = tid; i < LSQ; i += 512) E[i] = __expf(tr[i]);
  __syncthreads();  // the only block-wide barrier

  if (role != 0) {
    // == relay pair-unit: pu=(role-1)*4+pair -> d=2+pu/2 (2..63), par=pu&1 ===
    const int pair = tid >> 7;
    const int tp = tid & 127;
    const int wv = tp >> 6;
    const int rl = tp & 63;
    const bool act = rl < HL;
    const int lab = wv * HL + (act ? rl : HL - 1);
    const int pu = (role - 1) * 4 + pair;  // 0..123 exactly
    const int d = 2 + (pu >> 1);
    const int par = pu & 1;
    const int j = d & 7;
    u64* chain = acc + (size_t)(j * 4 + b) * Tn * Ln;
    const u64* axB = axp + (size_t)b * Tn * Ln;
    float R[Ln];
#pragma unroll
    for (int lp = 0; lp < Ln; ++lp) R[lp] = E[lp * Ln + lab];
    int wc = 1;
    const bool aHead = (d + KCH > Wn);
    const int t0 = d + (((d ^ par) & 1) ? 1 : 0);

    for (int t = t0; t < Tn; t += 2) {
      const int s = t - d;
      const int w = (t <= Wn) ? (s + 1) : (64 - d);
      while (w > wc) {
        ++wc;
#pragma unroll
        for (int lp = 0; lp < Ln; ++lp) R[lp] *= E[lp * Ln + lab];
      }
      const float segv = seg[SIDX(b, s + 1, t) + lab];
      const size_t tIdx = (size_t)t * Ln + lab;
      const bool head = aHead || (s < KCH);
      u64 ua = 0;
      if (!head) ua = __hip_atomic_load(&chain[tIdx], RLX, AGENT);

      u64 up = __hip_atomic_load(&axB[(size_t)s * Ln + lab], RLX, AGENT);
      while ((u32)(up >> 32) == SENT)
        up = __hip_atomic_load(&axB[(size_t)s * Ln + lab], RLX, AGENT);

      const int buf = (t >> 1) & 1;
      if (act) Alb_s[pair][buf][lab] = __uint_as_float((u32)up);
      if (rl == 0) CstS[pair][buf][wv] = __uint_as_float((u32)(up >> 32));
      LDSF();
      __hip_atomic_store(&stg[pair][wv], t, RLX, WG);
      while (__hip_atomic_load(&stg[pair][wv ^ 1], RLX, WG) < t) {}
      CBAR();
      const float C0 = CstS[pair][buf][0], C1 = CstS[pair][buf][1];
      MV1(Alb_s[pair][buf], R, Slo, Shi)
      const float c = comb(Slo, Shi, C0, C1, (float)w * segv);

      float m, v;
      if (head) {
        m = c;
        v = 1.f;
      } else {
        while (((ua >> 32) & 0xFFu) != (u32)(d + KCH))
          ua = __hip_atomic_load(&chain[tIdx], RLX, AGENT);
        const float pm = __uint_as_float((u32)ua);
        const float pv = __uint_as_float(((u32)(ua >> 32)) & ~0xFFu);
        const float nm = fmaxf(pm, c);
        v = pv * __expf(pm - nm) + __expf(c - nm);
        m = nm;
      }
      if (act) {
        const u32 vb = (__float_as_uint(v) & ~0xFFu) | (u32)d;
        __hip_atomic_store(&chain[tIdx],
                           (u64)__float_as_uint(m) | ((u64)vb << 32), RLX,
                           AGENT);
      }
    }
    return;
  }

  // =========================== finalizer block =============================
  const int w6 = tid >> 6;
  const int l = tid & 63;
  const bool act = l < HL;
  if (w6 >= 6) return;

  if (w6 < 2) {
    // ---- CORE wave h: bf16 matvec + merge {c1, REST} + publish ------------
    const int h = w6;
    const int lab = h * HL + (act ? l : HL - 1);
    u64* axpB = axp + (size_t)b * Tn * Ln;
    float R1[Ln];
#pragma unroll
    for (int lp = 0; lp < Ln; ++lp) R1[lp] = E[lp * Ln + lab];
    int w1c = 1;
    {  // seed t=0: alpha0 = exp(seg[b,0,0,:]+bos) (reference stores exp'd)
      const float bos = tr[LSQ + lab];
      const float a0 = __expf(seg[SIDX(b, 0, 0) + lab] + bos);
      const float Cw = wavemax48(act ? a0 : NEGINF);
      const float ax0 = __expf(a0 - Cw);
      if (act) __hip_atomic_store(&axpB[lab], pack2(ax0, Cw), RLX, AGENT);
      if (act) AlbRh[0][lab] = tobf16(ax0);
      if (l == 0) CRng[0][h] = Cw;
      LDSF();
      __hip_atomic_store(&seqA[h], 0, RLX, WG);
    }
    float s1q0 = seg[SIDX(b, 1, 1) + lab];
    float s1q1 = seg[SIDX(b, 2, 2) + lab];

    for (int t = 1; t < Tn; ++t) {
      const int s = t - 1;
      const float s1 = s1q0;
      s1q0 = s1q1;
      if (t + 2 < Tn) s1q1 = seg[SIDX(b, t + 2, t + 2) + lab];
      const int w1 = (t <= Wn) ? t : Wn;
      if (w1 > w1c) {
        w1c = w1;
#pragma unroll
        for (int lp = 0; lp < Ln; ++lp) R1[lp] *= E[lp * Ln + lab];
      }
      while (__hip_atomic_load(&seqA[h ^ 1], RLX, WG) < s) {}
      CBAR();
      const float C0 = CRng[s & 7][0], C1 = CRng[s & 7][1];
      MVB(AlbRh[s & 7], R1, Slo, Shi)
      const float c1 = comb(Slo, Shi, C0, C1, (float)w1 * s1);
      while (__hip_atomic_load(&rq[t & 1][h], RLX, WG) < t) {}
      CBAR();
      const float mr = RESTm[t & 3][lab], vr = RESTv[t & 3][lab];
      const float M = fmaxf(c1, mr);
      const float vs = __expf(c1 - M) + vr * __expf(mr - M);
      const float alpha = M + __logf(vs);
      const float Cw = wavemax48(act ? alpha : NEGINF);
      const float axn = __expf(alpha - Cw);
      // publish to relays FIRST (fire-and-forget agent store)
      if (act)
        __hip_atomic_store(&axpB[(size_t)t * Ln + lab], pack2(axn, Cw), RLX,
                           AGENT);
      if (act) AlbRh[t & 7][lab] = tobf16(axn);
      if (l == 0) CRng[t & 7][h] = Cw;
      LDSF();
      __hip_atomic_store(&seqA[h], t, RLX, WG);
      if (t == Tn - 1) {
        const float sm = wsumred(act ? axn : 0.f);
        const float Gw = Cw + __logf(sm);
        if (l == 0) redbuf[h] = Gw;
        LDSF();
        __hip_atomic_store(&rfl[h], 1, RLX, WG);
        if (h == 0 && l == 0) {
          while (__hip_atomic_load(&rfl[1], RLX, WG) < 1) {}
          CBAR();
          const float G0 = redbuf[0], G1 = redbuf[1];
          const float Mx = fmaxf(G0, G1);
          out[b] = Mx + __logf(__expf(G0 - Mx) + __expf(G1 - Mx));
        }
      }
    }
    return;
  }

  {
    // ---- REST wave (w6=2..5): parity p, half h; stride 2 ------------------
    // 8 chain ends + z. Ends 2,3 loaded FRESH each iteration (top); ends>=4
    // stride-2 prefetched. endd[j] = j>=2 ? j : j+8.
    const int p = (w6 - 2) >> 1;
    const int h = (w6 - 2) & 1;
    const int lab = h * HL + (act ? l : HL - 1);
    const float bos = tr[LSQ + lab];
    const int endd[8] = {8, 9, 2, 3, 4, 5, 6, 7};
    const int t0 = (p == 1) ? 1 : 2;
    float zq0 = (t0 <= Wn) ? seg[SIDX(b, 0, t0) + lab] : 0.f;
    float zq1 = (t0 + 2 <= Wn) ? seg[SIDX(b, 0, t0 + 2) + lab] : 0.f;
    u64 u[8];
#pragma unroll
    for (int jj = 0; jj < 8; ++jj) {
      u[jj] = 0;
      if (jj != 2 && jj != 3 && t0 >= endd[jj])
        u[jj] = __hip_atomic_load(
            &acc[(((size_t)jj * 4 + b) * Tn + t0) * Ln + lab], RLX, AGENT);
    }

    for (int t = t0; t < Tn; t += 2) {
      // fresh issues for the tight-slack ends (d=2,3)
      if (t >= 2)
        u[2] = __hip_atomic_load(
            &acc[(((size_t)2 * 4 + b) * Tn + t) * Ln + lab], RLX, AGENT);
      if (t >= 3)
        u[3] = __hip_atomic_load(
            &acc[(((size_t)3 * 4 + b) * Tn + t) * Ln + lab], RLX, AGENT);
      const float szv = zq0;
      zq0 = zq1;
      if (t + 4 <= Wn) zq1 = seg[SIDX(b, 0, t + 4) + lab];

      const float zv = (t <= Wn) ? (float)(t + 1) * (szv + bos) : NEGINF;
      float M = zv;
      float em[8], ev[8];
      // validate prefetched ends first (latency of fresh 2,3 hides here)
#pragma unroll
      for (int jj = 0; jj < 8; ++jj) {
        if (jj == 2 || jj == 3) continue;
        if (t >= endd[jj]) {
          const size_t aIdx = (((size_t)jj * 4 + b) * Tn + t) * Ln + lab;
          while (((u[jj] >> 32) & 0xFFu) != (u32)endd[jj])
            u[jj] = __hip_atomic_load(&acc[aIdx], RLX, AGENT);
          em[jj] = __uint_as_float((u32)u[jj]);
          ev[jj] = __uint_as_float(((u32)(u[jj] >> 32)) & ~0xFFu);
          M = fmaxf(M, em[jj]);
        } else {
          em[jj] = NEGINF;
          ev[jj] = 0.f;
        }
      }
#pragma unroll
      for (int jj = 2; jj <= 3; ++jj) {
        if (t >= endd[jj]) {
          const size_t aIdx = (((size_t)jj * 4 + b) * Tn + t) * Ln + lab;
          while (((u[jj] >> 32) & 0xFFu) != (u32)endd[jj])
            u[jj] = __hip_atomic_load(&acc[aIdx], RLX, AGENT);
          em[jj] = __uint_as_float((u32)u[jj]);
          ev[jj] = __uint_as_float(((u32)(u[jj] >> 32)) & ~0xFFu);
          M = fmaxf(M, em[jj]);
        } else {
          em[jj] = NEGINF;
          ev[jj] = 0.f;
        }
      }
      float vs = __expf(zv - M);
#pragma unroll
      for (int jj = 0; jj < 8; ++jj) vs += ev[jj] * __expf(em[jj] - M);

      if (act) {
        RESTm[t & 3][lab] = M;
        RESTv[t & 3][lab] = vs;
      }
      LDSF();
      __hip_atomic_store(&rq[p][h], t, RLX, WG);

      const int tn = t + 2;  // stride-2 prefetch for ends>=4
      if (tn < Tn) {
#pragma unroll
        for (int jj = 0; jj < 8; ++jj)
          if (jj != 2 && jj != 3 && tn >= endd[jj])
            u[jj] = __hip_atomic_load(
                &acc[(((size_t)jj * 4 + b) * Tn + tn) * Ln + lab], RLX, AGENT);
      }
    }
    return;
  }
}

extern "C" void kernel_launch(void* const* d_in, const int* in_sizes, int n_in,
                              void* d_out, int out_size, void* d_ws,
                              size_t ws_size, hipStream_t stream) {
  const float* seg = (const float*)d_in[0];  // (4,512,512,96) f32
  const float* tr = (const float*)d_in[1];   // (97,96) f32
  float* out = (float*)d_out;                // (4,) f32

  u64* axp = (u64*)d_ws;                 // [4][512][96]
  u64* acc = axp + (size_t)4 * Tn * Ln;  // [8][4][512][96]

  hipLaunchKernelGGL(init_ws, dim3(2048), dim3(256), 0, stream, (u64*)d_ws);
  hipLaunchKernelGGL(semicrf, dim3(4 * NROLE), dim3(512), 0, stream, seg, tr,
                     out, axp, acc);
}

// Round 16
// 857.212 us; speedup vs baseline: 1.0056x; 1.0056x over previous
//
#include <hip/hip_runtime.h>

// Semi-CRF log-partition. B=4, T=512, L=96, W=63.
// v16 = v11 (724us, best) with 2-TARGETS-PER-ITERATION fusion everywhere:
// per-iteration overhead (flag detects, publishes, bookkeeping) was ~1us of
// v11's 1.42us/step; fusing targets t=2k+1,2k+2 into one iteration halves it.
//  - CORE waves 0,1 (halves): t1 matvec -> merge -> publish -> half-exchange
//    (ring+LDSF+flag+detect) -> t2 matvec vs fresh alpha[t1] -> merge/publish.
//  - helpers one wave/half: d2 (w2,3), d3 (w4,5), REST chains+z (w6,7); each
//    processes both targets per iteration, flags after each target.
//  - alpha ring in bf16 (MVB): halves LDS-pipe load of 6 matvec waves.
//  - relays: v11 parity-split d=4..63, 8 interleaved chains, verbatim.
// Handoffs: 8B relaxed agent atomics (axp NaN sentinel, chain tag in low 8
// mantissa bits of v); LDS flags relaxed + lgkmcnt(0) only. VGPR<=128.

#define Tn 512
#define Ln 96
#define HL 48
#define LSQ (Ln * Ln)
#define Wn 63
#define KCH 8
#define NROLE 31  // 1 finalizer + 30 relay roles (4 pair-units each) per batch
#define NEGINF (-1e30f)
#define SENT 0x7FC00000u

#define AGENT __HIP_MEMORY_SCOPE_AGENT
#define WG __HIP_MEMORY_SCOPE_WORKGROUP
#define RLX __ATOMIC_RELAXED
#define LDSF() asm volatile("s_waitcnt lgkmcnt(0)" ::: "memory")
#define CBAR() asm volatile("" ::: "memory")
#define SIDX(b, i, t) ((((size_t)(b) * Tn + (i)) * Tn + (t)) * Ln)

typedef unsigned long long u64;
typedef unsigned int u32;
typedef unsigned short u16;

__device__ __forceinline__ float wsumred(float v) {
#pragma unroll
  for (int m = 32; m >= 1; m >>= 1) v += __shfl_xor(v, m, 64);
  return v;
}
__device__ __forceinline__ u64 pack2(float lo, float hi) {
  return (u64)__float_as_uint(lo) | ((u64)__float_as_uint(hi) << 32);
}
__device__ __forceinline__ u16 tobf16(float x) {
  return (u16)((__float_as_uint(x) + 0x8000u) >> 16);
}
__device__ __forceinline__ float wavemax48(float v) {
  int x;
  x = __builtin_amdgcn_update_dpp(__float_as_int(v), __float_as_int(v), 0xB1,
                                  0xF, 0xF, false);
  v = fmaxf(v, __int_as_float(x));
  x = __builtin_amdgcn_update_dpp(__float_as_int(v), __float_as_int(v), 0x4E,
                                  0xF, 0xF, false);
  v = fmaxf(v, __int_as_float(x));
  x = __builtin_amdgcn_update_dpp(__float_as_int(v), __float_as_int(v), 0x141,
                                  0xF, 0xF, false);
  v = fmaxf(v, __int_as_float(x));
  x = __builtin_amdgcn_update_dpp(__float_as_int(v), __float_as_int(v), 0x140,
                                  0xF, 0xF, false);
  v = fmaxf(v, __int_as_float(x));
  float r0 = __int_as_float(__builtin_amdgcn_readlane(__float_as_int(v), 0));
  float r1 = __int_as_float(__builtin_amdgcn_readlane(__float_as_int(v), 16));
  float r2 = __int_as_float(__builtin_amdgcn_readlane(__float_as_int(v), 32));
  float r3 = __int_as_float(__builtin_amdgcn_readlane(__float_as_int(v), 48));
  return fmaxf(fmaxf(r0, r1), fmaxf(r2, r3));
}
__device__ __forceinline__ float comb(float Slo, float Shi, float C0, float C1,
                                      float wseg) {
  const float Cm = fmaxf(C0, C1);
  return Cm + wseg + __logf(__expf(C0 - Cm) * Slo + __expf(C1 - Cm) * Shi);
}

// f32 matvec (relays): 24 ds_read_b128
#define MV1(SRC, RR, SLO, SHI)                                       \
  float SLO, SHI;                                                    \
  {                                                                  \
    const float4* A4 = (const float4*)(SRC);                         \
    float a0 = 0, a1 = 0, a2 = 0, a3 = 0;                            \
    _Pragma("unroll") for (int q = 0; q < 12; ++q) {                 \
      float4 a = A4[q];                                              \
      a0 = fmaf(a.x, RR[4 * q + 0], a0);                             \
      a1 = fmaf(a.y, RR[4 * q + 1], a1);                             \
      a2 = fmaf(a.z, RR[4 * q + 2], a2);                             \
      a3 = fmaf(a.w, RR[4 * q + 3], a3);                             \
    }                                                                \
    SLO = (a0 + a1) + (a2 + a3);                                     \
    float b0 = 0, b1 = 0, b2 = 0, b3 = 0;                            \
    _Pragma("unroll") for (int q = 12; q < 24; ++q) {                \
      float4 a = A4[q];                                              \
      b0 = fmaf(a.x, RR[4 * q + 0], b0);                             \
      b1 = fmaf(a.y, RR[4 * q + 1], b1);                             \
      b2 = fmaf(a.z, RR[4 * q + 2], b2);                             \
      b3 = fmaf(a.w, RR[4 * q + 3], b3);                             \
    }                                                                \
    SHI = (b0 + b1) + (b2 + b3);                                     \
  }

// bf16 matvec (finalizer): 12 ds_read_b128, shift/and unpack
#define MVB(SRC, RR, SLO, SHI)                                               \
  float SLO, SHI;                                                            \
  {                                                                          \
    const uint4* A4 = (const uint4*)(SRC);                                   \
    float a0 = 0, a1 = 0, a2 = 0, a3 = 0;                                    \
    _Pragma("unroll") for (int q = 0; q < 6; ++q) {                          \
      uint4 a = A4[q];                                                       \
      a0 = fmaf(__uint_as_float(a.x << 16), RR[8 * q + 0], a0);              \
      a1 = fmaf(__uint_as_float(a.x & 0xFFFF0000u), RR[8 * q + 1], a1);      \
      a2 = fmaf(__uint_as_float(a.y << 16), RR[8 * q + 2], a2);              \
      a3 = fmaf(__uint_as_float(a.y & 0xFFFF0000u), RR[8 * q + 3], a3);      \
      a0 = fmaf(__uint_as_float(a.z << 16), RR[8 * q + 4], a0);              \
      a1 = fmaf(__uint_as_float(a.z & 0xFFFF0000u), RR[8 * q + 5], a1);      \
      a2 = fmaf(__uint_as_float(a.w << 16), RR[8 * q + 6], a2);              \
      a3 = fmaf(__uint_as_float(a.w & 0xFFFF0000u), RR[8 * q + 7], a3);      \
    }                                                                        \
    SLO = (a0 + a1) + (a2 + a3);                                             \
    float b0 = 0, b1 = 0, b2 = 0, b3 = 0;                                    \
    _Pragma("unroll") for (int q = 6; q < 12; ++q) {                         \
      uint4 a = A4[q];                                                       \
      b0 = fmaf(__uint_as_float(a.x << 16), RR[8 * q + 0], b0);              \
      b1 = fmaf(__uint_as_float(a.x & 0xFFFF0000u), RR[8 * q + 1], b1);      \
      b2 = fmaf(__uint_as_float(a.y << 16), RR[8 * q + 2], b2);              \
      b3 = fmaf(__uint_as_float(a.y & 0xFFFF0000u), RR[8 * q + 3], b3);      \
      b0 = fmaf(__uint_as_float(a.z << 16), RR[8 * q + 4], b0);              \
      b1 = fmaf(__uint_as_float(a.z & 0xFFFF0000u), RR[8 * q + 5], b1);      \
      b2 = fmaf(__uint_as_float(a.w << 16), RR[8 * q + 6], b2);              \
      b3 = fmaf(__uint_as_float(a.w & 0xFFFF0000u), RR[8 * q + 7], b3);      \
    }                                                                        \
    SHI = (b0 + b1) + (b2 + b3);                                             \
  }

__global__ void init_ws(u64* ws) {
  const size_t n1 = (size_t)4 * Tn * Ln;
  const size_t n = n1 * 9;  // axp + 8 chains
  for (size_t i = (size_t)blockIdx.x * blockDim.x + threadIdx.x; i < n;
       i += (size_t)gridDim.x * blockDim.x)
    ws[i] = (i < n1) ? (((u64)SENT) << 32) : 0ull;
}

__global__ __launch_bounds__(512, 1) void semicrf(
    const float* __restrict__ seg, const float* __restrict__ tr,
    float* __restrict__ out, u64* axp, u64* acc) {
  const int b = blockIdx.x / NROLE;
  const int role = blockIdx.x % NROLE;
  const int tid = threadIdx.x;

  __shared__ __align__(16) float E[LSQ];           // exp(trans) 36 KB
  __shared__ __align__(16) u16 AlbRh[8][Ln];       // bf16 alpha ring
  __shared__ float CRng[8][2];                     // per-half C ring
  __shared__ __align__(16) float slotC2[4][Ln];    // d2 contributions
  __shared__ __align__(16) float slotC3[4][Ln];    // d3 contributions
  __shared__ float RESTm[4][Ln];                   // chains+z merge (m)
  __shared__ float RESTv[4][Ln];                   // chains+z merge (v)
  __shared__ __align__(16) float Alb_s[4][2][Ln];  // relay staging (dbuf)
  __shared__ float CstS[4][2][2];
  __shared__ float redbuf[2];
  __shared__ int seqH[2], sp2[2], sp3[2], rq[2], rfl[2];
  __shared__ int stg[4][2];

  if (tid < 2) {
    seqH[tid] = -1;
    sp2[tid] = -1;
    sp3[tid] = -1;
    rq[tid] = -1;
    rfl[tid] = -1;
  }
  if (tid < 8) stg[tid >> 1][tid & 1] = -1;
  for (int i = tid; i < LSQ; i += 512) E[i] = __expf(tr[i]);
  __syncthreads();  // the only block-wide barrier

  if (role != 0) {
    // ===== relay pair-unit (v11 verbatim): d=4+pu/2, parity pu&1 ===========
    const int pair = tid >> 7;
    const int tp = tid & 127;
    const int wv = tp >> 6;
    const int rl = tp & 63;
    const bool act = rl < HL;
    const int lab = wv * HL + (act ? rl : HL - 1);
    const int pu = (role - 1) * 4 + pair;
    const int d = 4 + (pu >> 1);
    const int par = pu & 1;
    const int j = d & 7;
    u64* chain = acc + (size_t)(j * 4 + b) * Tn * Ln;
    const u64* axB = axp + (size_t)b * Tn * Ln;
    float R[Ln];
#pragma unroll
    for (int lp = 0; lp < Ln; ++lp) R[lp] = E[lp * Ln + lab];
    int wc = 1;
    const bool aHead = (d + KCH > Wn);
    const int t0 = d + (((d ^ par) & 1) ? 1 : 0);

    for (int t = t0; t < Tn; t += 2) {
      const int s = t - d;
      const int w = (t <= Wn) ? (s + 1) : (64 - d);
      while (w > wc) {
        ++wc;
#pragma unroll
        for (int lp = 0; lp < Ln; ++lp) R[lp] *= E[lp * Ln + lab];
      }
      const float segv = seg[SIDX(b, s + 1, t) + lab];
      const size_t tIdx = (size_t)t * Ln + lab;
      const bool head = aHead || (s < KCH);
      u64 ua = 0;
      if (!head) ua = __hip_atomic_load(&chain[tIdx], RLX, AGENT);

      u64 up = __hip_atomic_load(&axB[(size_t)s * Ln + lab], RLX, AGENT);
      while ((u32)(up >> 32) == SENT)
        up = __hip_atomic_load(&axB[(size_t)s * Ln + lab], RLX, AGENT);

      const int buf = (t >> 1) & 1;
      if (act) Alb_s[pair][buf][lab] = __uint_as_float((u32)up);
      if (rl == 0) CstS[pair][buf][wv] = __uint_as_float((u32)(up >> 32));
      LDSF();
      __hip_atomic_store(&stg[pair][wv], t, RLX, WG);
      while (__hip_atomic_load(&stg[pair][wv ^ 1], RLX, WG) < t) {}
      CBAR();
      const float C0 = CstS[pair][buf][0], C1 = CstS[pair][buf][1];
      MV1(Alb_s[pair][buf], R, Slo, Shi)
      const float c = comb(Slo, Shi, C0, C1, (float)w * segv);

      float m, v;
      if (head) {
        m = c;
        v = 1.f;
      } else {
        while (((ua >> 32) & 0xFFu) != (u32)(d + KCH))
          ua = __hip_atomic_load(&chain[tIdx], RLX, AGENT);
        const float pm = __uint_as_float((u32)ua);
        const float pv = __uint_as_float(((u32)(ua >> 32)) & ~0xFFu);
        const float nm = fmaxf(pm, c);
        v = pv * __expf(pm - nm) + __expf(c - nm);
        m = nm;
      }
      if (act) {
        const u32 vb = (__float_as_uint(v) & ~0xFFu) | (u32)d;
        __hip_atomic_store(&chain[tIdx],
                           (u64)__float_as_uint(m) | ((u64)vb << 32), RLX,
                           AGENT);
      }
    }
    return;
  }

  // =========================== finalizer block =============================
  const int w6 = tid >> 6;
  const int l = tid & 63;
  const bool act = l < HL;

  if (w6 < 2) {
    // ---- CORE wave h: 2 targets/iteration ---------------------------------
    const int h = w6;
    const int lab = h * HL + (act ? l : HL - 1);
    u64* axpB = axp + (size_t)b * Tn * Ln;
    float R1[Ln];
#pragma unroll
    for (int lp = 0; lp < Ln; ++lp) R1[lp] = E[lp * Ln + lab];
    int w1c = 1;
    {  // seed t=0
      const float bos = tr[LSQ + lab];
      const float a0 = __expf(seg[SIDX(b, 0, 0) + lab] + bos);
      const float Cw = wavemax48(act ? a0 : NEGINF);
      const float ax0 = __expf(a0 - Cw);
      if (act) __hip_atomic_store(&axpB[lab], pack2(ax0, Cw), RLX, AGENT);
      if (act) AlbRh[0][lab] = tobf16(ax0);
      if (l == 0) CRng[0][h] = Cw;
      LDSF();
      __hip_atomic_store(&seqH[h], 0, RLX, WG);
    }
    float qa = seg[SIDX(b, 1, 1) + lab];       // diag t=1
    float qb = seg[SIDX(b, 2, 2) + lab];       // diag t=2
    float qa2 = seg[SIDX(b, 3, 3) + lab];      // diag t=3
    float qb2 = seg[SIDX(b, 4, 4) + lab];      // diag t=4

    for (int k = 0; k < 256; ++k) {
      const int t1 = 2 * k + 1, t2 = 2 * k + 2;
      const float s1 = qa, s2 = qb;
      qa = qa2;
      qb = qb2;
      if (t1 + 4 < Tn) qa2 = seg[SIDX(b, t1 + 4, t1 + 4) + lab];
      if (t2 + 4 < Tn) qb2 = seg[SIDX(b, t2 + 4, t2 + 4) + lab];

      // ================= target t1 =================
      const int w1 = (t1 <= Wn) ? t1 : Wn;
      if (w1 > w1c) {
        w1c = w1;
#pragma unroll
        for (int lp = 0; lp < Ln; ++lp) R1[lp] *= E[lp * Ln + lab];
      }
      while (__hip_atomic_load(&seqH[h ^ 1], RLX, WG) < t1 - 1) {}
      CBAR();
      const float C0a = CRng[(t1 - 1) & 7][0], C1a = CRng[(t1 - 1) & 7][1];
      MVB(AlbRh[(t1 - 1) & 7], R1, SloA, ShiA)
      const float c1a = comb(SloA, ShiA, C0a, C1a, (float)w1 * s1);
      float c2a = NEGINF, c3a = NEGINF;
      if (t1 >= 2) {
        while (__hip_atomic_load(&sp2[h], RLX, WG) < t1) {}
        CBAR();
        c2a = slotC2[t1 & 3][lab];
      }
      if (t1 >= 3) {
        while (__hip_atomic_load(&sp3[h], RLX, WG) < t1) {}
        CBAR();
        c3a = slotC3[t1 & 3][lab];
      }
      while (__hip_atomic_load(&rq[h], RLX, WG) < t1) {}
      CBAR();
      const float mra = RESTm[t1 & 3][lab], vra = RESTv[t1 & 3][lab];
      const float Ma = fmaxf(fmaxf(c1a, c2a), fmaxf(c3a, mra));
      const float vsa = __expf(c1a - Ma) + __expf(c2a - Ma) +
                        __expf(c3a - Ma) + vra * __expf(mra - Ma);
      const float alpha1 = Ma + __logf(vsa);
      const float Cw1 = wavemax48(act ? alpha1 : NEGINF);
      const float ax1 = __expf(alpha1 - Cw1);
      if (act)
        __hip_atomic_store(&axpB[(size_t)t1 * Ln + lab], pack2(ax1, Cw1), RLX,
                           AGENT);
      if (act) AlbRh[t1 & 7][lab] = tobf16(ax1);
      if (l == 0) CRng[t1 & 7][h] = Cw1;
      LDSF();
      __hip_atomic_store(&seqH[h], t1, RLX, WG);

      if (t1 == Tn - 1) {  // k=255: t1=511 is the last target
        const float sm = wsumred(act ? ax1 : 0.f);
        const float Gw = Cw1 + __logf(sm);
        if (l == 0) redbuf[h] = Gw;
        LDSF();
        __hip_atomic_store(&rfl[h], 1, RLX, WG);
        if (h == 0 && l == 0) {
          while (__hip_atomic_load(&rfl[1], RLX, WG) < 1) {}
          CBAR();
          const float G0 = redbuf[0], G1 = redbuf[1];
          const float Mx = fmaxf(G0, G1);
          out[b] = Mx + __logf(__expf(G0 - Mx) + __expf(G1 - Mx));
        }
        break;
      }

      // ================= target t2 =================
      const int w2 = (t2 <= Wn) ? t2 : Wn;
      if (w2 > w1c) {
        w1c = w2;
#pragma unroll
        for (int lp = 0; lp < Ln; ++lp) R1[lp] *= E[lp * Ln + lab];
      }
      while (__hip_atomic_load(&seqH[h ^ 1], RLX, WG) < t1) {}
      CBAR();
      const float C0b = CRng[t1 & 7][0], C1b = CRng[t1 & 7][1];
      MVB(AlbRh[t1 & 7], R1, SloB, ShiB)
      const float c1b = comb(SloB, ShiB, C0b, C1b, (float)w2 * s2);
      while (__hip_atomic_load(&sp2[h], RLX, WG) < t2) {}
      CBAR();
      const float c2b = slotC2[t2 & 3][lab];
      float c3b = NEGINF;
      if (t2 >= 3) {
        while (__hip_atomic_load(&sp3[h], RLX, WG) < t2) {}
        CBAR();
        c3b = slotC3[t2 & 3][lab];
      }
      while (__hip_atomic_load(&rq[h], RLX, WG) < t2) {}
      CBAR();
      const float mrb = RESTm[t2 & 3][lab], vrb = RESTv[t2 & 3][lab];
      const float Mb = fmaxf(fmaxf(c1b, c2b), fmaxf(c3b, mrb));
      const float vsb = __expf(c1b - Mb) + __expf(c2b - Mb) +
                        __expf(c3b - Mb) + vrb * __expf(mrb - Mb);
      const float alpha2 = Mb + __logf(vsb);
      const float Cw2 = wavemax48(act ? alpha2 : NEGINF);
      const float ax2 = __expf(alpha2 - Cw2);
      if (act)
        __hip_atomic_store(&axpB[(size_t)t2 * Ln + lab], pack2(ax2, Cw2), RLX,
                           AGENT);
      if (act) AlbRh[t2 & 7][lab] = tobf16(ax2);
      if (l == 0) CRng[t2 & 7][h] = Cw2;
      LDSF();
      __hip_atomic_store(&seqH[h], t2, RLX, WG);
    }
    return;
  }

  if (w6 < 4) {
    // ---- d2 wave (half h): 2 targets/iteration ----------------------------
    const int h = w6 - 2;
    const int lab = h * HL + (act ? l : HL - 1);
    float R[Ln];
#pragma unroll
    for (int lp = 0; lp < Ln; ++lp) R[lp] = E[lp * Ln + lab];
    int wc = 1;
    // seg[b, t-1, t]; first valid targets: t2=2 (k=0), t1=3 (k=1)
    float q1 = seg[SIDX(b, 2, 3) + lab];   // t1=3
    float q2 = seg[SIDX(b, 1, 2) + lab];   // t2=2
    float q1n = seg[SIDX(b, 4, 5) + lab];  // t1=5
    float q2n = seg[SIDX(b, 3, 4) + lab];  // t2=4

    for (int k = 0; k < 256; ++k) {
      const int t1 = 2 * k + 1, t2 = 2 * k + 2;
      const float sv1 = q1, sv2 = q2;
      q1 = q1n;
      q2 = q2n;
      if (t1 + 4 < Tn) q1n = seg[SIDX(b, t1 + 3, t1 + 4) + lab];
      if (t2 + 4 < Tn) q2n = seg[SIDX(b, t2 + 3, t2 + 4) + lab];

      if (t1 >= 3) {  // target t1 (needs ring[t1-2])
        const int w = (t1 <= Wn) ? (t1 - 1) : 62;
        if (w > wc) {
          wc = w;
#pragma unroll
          for (int lp = 0; lp < Ln; ++lp) R[lp] *= E[lp * Ln + lab];
        }
        while (__hip_atomic_load(&seqH[0], RLX, WG) < t1 - 2 ||
               __hip_atomic_load(&seqH[1], RLX, WG) < t1 - 2) {}
        CBAR();
        const float C0 = CRng[(t1 - 2) & 7][0], C1 = CRng[(t1 - 2) & 7][1];
        MVB(AlbRh[(t1 - 2) & 7], R, SloA, ShiA)
        const float c = comb(SloA, ShiA, C0, C1, (float)w * sv1);
        if (act) slotC2[t1 & 3][lab] = c;
        LDSF();
        __hip_atomic_store(&sp2[h], t1, RLX, WG);
      }
      if (t2 < Tn) {  // target t2 (needs ring[t2-2])
        const int w = (t2 <= Wn) ? (t2 - 1) : 62;
        if (w > wc) {
          wc = w;
#pragma unroll
          for (int lp = 0; lp < Ln; ++lp) R[lp] *= E[lp * Ln + lab];
        }
        while (__hip_atomic_load(&seqH[0], RLX, WG) < t2 - 2 ||
               __hip_atomic_load(&seqH[1], RLX, WG) < t2 - 2) {}
        CBAR();
        const float C0 = CRng[(t2 - 2) & 7][0], C1 = CRng[(t2 - 2) & 7][1];
        MVB(AlbRh[(t2 - 2) & 7], R, SloB, ShiB)
        const float c = comb(SloB, ShiB, C0, C1, (float)w * sv2);
        if (act) slotC2[t2 & 3][lab] = c;
        LDSF();
        __hip_atomic_store(&sp2[h], t2, RLX, WG);
      }
    }
    return;
  }

  if (w6 < 6) {
    // ---- d3 wave (half h): 2 targets/iteration ----------------------------
    const int h = w6 - 4;
    const int lab = h * HL + (act ? l : HL - 1);
    float R[Ln];
#pragma unroll
    for (int lp = 0; lp < Ln; ++lp) R[lp] = E[lp * Ln + lab];
    int wc = 1;
    // seg[b, t-2, t]; first valid targets: t1=3 (k=1), t2=4 (k=1)
    float q1 = seg[SIDX(b, 1, 3) + lab];   // t1=3
    float q2 = seg[SIDX(b, 2, 4) + lab];   // t2=4
    float q1n = seg[SIDX(b, 3, 5) + lab];  // t1=5
    float q2n = seg[SIDX(b, 4, 6) + lab];  // t2=6

    for (int k = 0; k < 256; ++k) {
      const int t1 = 2 * k + 1, t2 = 2 * k + 2;
      const float sv1 = q1, sv2 = q2;
      q1 = q1n;
      q2 = q2n;
      if (t1 + 4 < Tn) q1n = seg[SIDX(b, t1 + 2, t1 + 4) + lab];
      if (t2 + 4 < Tn) q2n = seg[SIDX(b, t2 + 2, t2 + 4) + lab];

      if (t1 >= 3) {
        const int w = (t1 <= Wn) ? (t1 - 2) : 61;
        if (w > wc) {
          wc = w;
#pragma unroll
          for (int lp = 0; lp < Ln; ++lp) R[lp] *= E[lp * Ln + lab];
        }
        while (__hip_atomic_load(&seqH[0], RLX, WG) < t1 - 3 ||
               __hip_atomic_load(&seqH[1], RLX, WG) < t1 - 3) {}
        CBAR();
        const float C0 = CRng[(t1 - 3) & 7][0], C1 = CRng[(t1 - 3) & 7][1];
        MVB(AlbRh[(t1 - 3) & 7], R, SloA, ShiA)
        const float c = comb(SloA, ShiA, C0, C1, (float)w * sv1);
        if (act) slotC3[t1 & 3][lab] = c;
        LDSF();
        __hip_atomic_store(&sp3[h], t1, RLX, WG);
      }
      if (t2 >= 3 && t2 < Tn) {
        const int w = (t2 <= Wn) ? (t2 - 2) : 61;
        if (w > wc) {
          wc = w;
#pragma unroll
          for (int lp = 0; lp < Ln; ++lp) R[lp] *= E[lp * Ln + lab];
        }
        while (__hip_atomic_load(&seqH[0], RLX, WG) < t2 - 3 ||
               __hip_atomic_load(&seqH[1], RLX, WG) < t2 - 3) {}
        CBAR();
        const float C0 = CRng[(t2 - 3) & 7][0], C1 = CRng[(t2 - 3) & 7][1];
        MVB(AlbRh[(t2 - 3) & 7], R, SloB, ShiB)
        const float c = comb(SloB, ShiB, C0, C1, (float)w * sv2);
        if (act) slotC3[t2 & 3][lab] = c;
        LDSF();
        __hip_atomic_store(&sp3[h], t2, RLX, WG);
      }
    }
    return;
  }

  {
    // ---- REST wave (half h): chains+z, 2 targets/iteration ----------------
    const int h = w6 - 6;
    const int lab = h * HL + (act ? l : HL - 1);
    const float bos = tr[LSQ + lab];
    const int endd[8] = {8, 9, 10, 11, 4, 5, 6, 7};  // chain end per residue
    float z1 = seg[SIDX(b, 0, 1) + lab];
    float z2 = seg[SIDX(b, 0, 2) + lab];
    float z1n = seg[SIDX(b, 0, 3) + lab];
    float z2n = seg[SIDX(b, 0, 4) + lab];
    u64 u1[8], u2[8];
#pragma unroll
    for (int jj = 0; jj < 8; ++jj) {
      u1[jj] = 0;
      u2[jj] = 0;
    }

    for (int k = 0; k < 256; ++k) {
      const int t1 = 2 * k + 1, t2 = 2 * k + 2;
      const float sz1 = z1, sz2 = z2;
      z1 = z1n;
      z2 = z2n;
      if (t1 + 4 <= Wn) z1n = seg[SIDX(b, 0, t1 + 4) + lab];
      if (t2 + 4 <= Wn) z2n = seg[SIDX(b, 0, t2 + 4) + lab];

      // ---- target t1 ----
      {
        const float zv = (t1 <= Wn) ? (float)(t1 + 1) * (sz1 + bos) : NEGINF;
        float M = zv;
        float em[8], ev[8];
#pragma unroll
        for (int jj = 0; jj < 8; ++jj) {
          if (t1 >= endd[jj]) {
            const size_t aIdx = (((size_t)jj * 4 + b) * Tn + t1) * Ln + lab;
            while (((u1[jj] >> 32) & 0xFFu) != (u32)endd[jj])
              u1[jj] = __hip_atomic_load(&acc[aIdx], RLX, AGENT);
            em[jj] = __uint_as_float((u32)u1[jj]);
            ev[jj] = __uint_as_float(((u32)(u1[jj] >> 32)) & ~0xFFu);
            M = fmaxf(M, em[jj]);
          } else {
            em[jj] = NEGINF;
            ev[jj] = 0.f;
          }
        }
        float vs = __expf(zv - M);
#pragma unroll
        for (int jj = 0; jj < 8; ++jj) vs += ev[jj] * __expf(em[jj] - M);
        if (act) {
          RESTm[t1 & 3][lab] = M;
          RESTv[t1 & 3][lab] = vs;
        }
        LDSF();
        __hip_atomic_store(&rq[h], t1, RLX, WG);
      }
      // ---- target t2 ----
      if (t2 < Tn) {
        const float zv = (t2 <= Wn) ? (float)(t2 + 1) * (sz2 + bos) : NEGINF;
        float M = zv;
        float em[8], ev[8];
#pragma unroll
        for (int jj = 0; jj < 8; ++jj) {
          if (t2 >= endd[jj]) {
            const size_t aIdx = (((size_t)jj * 4 + b) * Tn + t2) * Ln + lab;
            while (((u2[jj] >> 32) & 0xFFu) != (u32)endd[jj])
              u2[jj] = __hip_atomic_load(&acc[aIdx], RLX, AGENT);
            em[jj] = __uint_as_float((u32)u2[jj]);
            ev[jj] = __uint_as_float(((u32)(u2[jj] >> 32)) & ~0xFFu);
            M = fmaxf(M, em[jj]);
          } else {
            em[jj] = NEGINF;
            ev[jj] = 0.f;
          }
        }
        float vs = __expf(zv - M);
#pragma unroll
        for (int jj = 0; jj < 8; ++jj) vs += ev[jj] * __expf(em[jj] - M);
        if (act) {
          RESTm[t2 & 3][lab] = M;
          RESTv[t2 & 3][lab] = vs;
        }
        LDSF();
        __hip_atomic_store(&rq[h], t2, RLX, WG);
      }
      // ---- prefetch chain ends for t1+2, t2+2 ----
      if (t1 + 2 < Tn) {
#pragma unroll
        for (int jj = 0; jj < 8; ++jj)
          if (t1 + 2 >= endd[jj])
            u1[jj] = __hip_atomic_load(
                &acc[(((size_t)jj * 4 + b) * Tn + (t1 + 2)) * Ln + lab], RLX,
                AGENT);
      }
      if (t2 + 2 < Tn) {
#pragma unroll
        for (int jj = 0; jj < 8; ++jj)
          if (t2 + 2 >= endd[jj])
            u2[jj] = __hip_atomic_load(
                &acc[(((size_t)jj * 4 + b) * Tn + (t2 + 2)) * Ln + lab], RLX,
                AGENT);
      }
    }
    return;
  }
}

extern "C" void kernel_launch(void* const* d_in, const int* in_sizes, int n_in,
                              void* d_out, int out_size, void* d_ws,
                              size_t ws_size, hipStream_t stream) {
  const float* seg = (const float*)d_in[0];  // (4,512,512,96) f32
  const float* tr = (const float*)d_in[1];   // (97,96) f32
  float* out = (float*)d_out;                // (4,) f32

  u64* axp = (u64*)d_ws;                 // [4][512][96]
  u64* acc = axp + (size_t)4 * Tn * Ln;  // [8][4][512][96]

  hipLaunchKernelGGL(init_ws, dim3(2048), dim3(256), 0, stream, (u64*)d_ws);
  hipLaunchKernelGGL(semicrf, dim3(4 * NROLE), dim3(512), 0, stream, seg, tr,
                     out, axp, acc);
}

// Round 17
// 757.225 us; speedup vs baseline: 1.1384x; 1.1320x over previous
//
#include <hip/hip_runtime.h>

// Semi-CRF log-partition. B=4, T=512, L=96, W=63.
// v17: finalizer = 8-wave BARRIER-LOCKSTEP pipeline (raw s_barrier, no vmcnt
// drain), ONE barrier/step, zero intra-block spin flags:
//   step t: core (waves 0,1) = d1 matvec vs ring[t-1] + merge slot2(t),
//           slot3(t), REST(t) + ring[t] write + axp publish;
//           d2 (2,3) produce slot2(t+1) vs ring[t-1]; d3 (4,5) slot3(t+1)
//           vs ring[t-2]; REST (6,7) produce chains+z(t+1), depth-2 prefetch.
// bf16 alpha ring (12 b128/matvec). Relays: v11 design, 3-WAY target split
// (t mod 3), d=4..63, 180 pair-units, 45 roles; chains per (d mod 8) x split.
// Handoffs: 8B relaxed agent atomics (axp NaN sentinel, chain tag in low 8
// mantissa bits of v); LDS ordering via lgkmcnt(0) + s_barrier.

#define Tn 512
#define Ln 96
#define HL 48
#define LSQ (Ln * Ln)
#define Wn 63
#define KCH 8
#define NROLE 46  // 1 finalizer + 45 relay roles (4 pair-units each) per batch
#define NEGINF (-1e30f)
#define SENT 0x7FC00000u

#define AGENT __HIP_MEMORY_SCOPE_AGENT
#define WG __HIP_MEMORY_SCOPE_WORKGROUP
#define RLX __ATOMIC_RELAXED
#define LDSF() asm volatile("s_waitcnt lgkmcnt(0)" ::: "memory")
#define CBAR() asm volatile("" ::: "memory")
#define BARRIER()                 \
  do {                            \
    LDSF();                       \
    CBAR();                       \
    __builtin_amdgcn_s_barrier(); \
    CBAR();                       \
  } while (0)
#define SIDX(b, i, t) ((((size_t)(b) * Tn + (i)) * Tn + (t)) * Ln)

typedef unsigned long long u64;
typedef unsigned int u32;
typedef unsigned short u16;

__device__ __forceinline__ float wsumred(float v) {
#pragma unroll
  for (int m = 32; m >= 1; m >>= 1) v += __shfl_xor(v, m, 64);
  return v;
}
__device__ __forceinline__ u64 pack2(float lo, float hi) {
  return (u64)__float_as_uint(lo) | ((u64)__float_as_uint(hi) << 32);
}
__device__ __forceinline__ u16 tobf16(float x) {
  return (u16)((__float_as_uint(x) + 0x8000u) >> 16);
}
__device__ __forceinline__ float wavemax48(float v) {
  int x;
  x = __builtin_amdgcn_update_dpp(__float_as_int(v), __float_as_int(v), 0xB1,
                                  0xF, 0xF, false);
  v = fmaxf(v, __int_as_float(x));
  x = __builtin_amdgcn_update_dpp(__float_as_int(v), __float_as_int(v), 0x4E,
                                  0xF, 0xF, false);
  v = fmaxf(v, __int_as_float(x));
  x = __builtin_amdgcn_update_dpp(__float_as_int(v), __float_as_int(v), 0x141,
                                  0xF, 0xF, false);
  v = fmaxf(v, __int_as_float(x));
  x = __builtin_amdgcn_update_dpp(__float_as_int(v), __float_as_int(v), 0x140,
                                  0xF, 0xF, false);
  v = fmaxf(v, __int_as_float(x));
  float r0 = __int_as_float(__builtin_amdgcn_readlane(__float_as_int(v), 0));
  float r1 = __int_as_float(__builtin_amdgcn_readlane(__float_as_int(v), 16));
  float r2 = __int_as_float(__builtin_amdgcn_readlane(__float_as_int(v), 32));
  float r3 = __int_as_float(__builtin_amdgcn_readlane(__float_as_int(v), 48));
  return fmaxf(fmaxf(r0, r1), fmaxf(r2, r3));
}
__device__ __forceinline__ float comb(float Slo, float Shi, float C0, float C1,
                                      float wseg) {
  const float Cm = fmaxf(C0, C1);
  return Cm + wseg + __logf(__expf(C0 - Cm) * Slo + __expf(C1 - Cm) * Shi);
}

// f32 matvec (relays): 24 ds_read_b128
#define MV1(SRC, RR, SLO, SHI)                                       \
  float SLO, SHI;                                                    \
  {                                                                  \
    const float4* A4 = (const float4*)(SRC);                         \
    float a0 = 0, a1 = 0, a2 = 0, a3 = 0;                            \
    _Pragma("unroll") for (int q = 0; q < 12; ++q) {                 \
      float4 a = A4[q];                                              \
      a0 = fmaf(a.x, RR[4 * q + 0], a0);                             \
      a1 = fmaf(a.y, RR[4 * q + 1], a1);                             \
      a2 = fmaf(a.z, RR[4 * q + 2], a2);                             \
      a3 = fmaf(a.w, RR[4 * q + 3], a3);                             \
    }                                                                \
    SLO = (a0 + a1) + (a2 + a3);                                     \
    float b0 = 0, b1 = 0, b2 = 0, b3 = 0;                            \
    _Pragma("unroll") for (int q = 12; q < 24; ++q) {                \
      float4 a = A4[q];                                              \
      b0 = fmaf(a.x, RR[4 * q + 0], b0);                             \
      b1 = fmaf(a.y, RR[4 * q + 1], b1);                             \
      b2 = fmaf(a.z, RR[4 * q + 2], b2);                             \
      b3 = fmaf(a.w, RR[4 * q + 3], b3);                             \
    }                                                                \
    SHI = (b0 + b1) + (b2 + b3);                                     \
  }

// bf16 matvec (finalizer): 12 ds_read_b128, shift/and unpack
#define MVB(SRC, RR, SLO, SHI)                                               \
  float SLO, SHI;                                                            \
  {                                                                          \
    const uint4* A4 = (const uint4*)(SRC);                                   \
    float a0 = 0, a1 = 0, a2 = 0, a3 = 0;                                    \
    _Pragma("unroll") for (int q = 0; q < 6; ++q) {                          \
      uint4 a = A4[q];                                                       \
      a0 = fmaf(__uint_as_float(a.x << 16), RR[8 * q + 0], a0);              \
      a1 = fmaf(__uint_as_float(a.x & 0xFFFF0000u), RR[8 * q + 1], a1);      \
      a2 = fmaf(__uint_as_float(a.y << 16), RR[8 * q + 2], a2);              \
      a3 = fmaf(__uint_as_float(a.y & 0xFFFF0000u), RR[8 * q + 3], a3);      \
      a0 = fmaf(__uint_as_float(a.z << 16), RR[8 * q + 4], a0);              \
      a1 = fmaf(__uint_as_float(a.z & 0xFFFF0000u), RR[8 * q + 5], a1);      \
      a2 = fmaf(__uint_as_float(a.w << 16), RR[8 * q + 6], a2);              \
      a3 = fmaf(__uint_as_float(a.w & 0xFFFF0000u), RR[8 * q + 7], a3);      \
    }                                                                        \
    SLO = (a0 + a1) + (a2 + a3);                                             \
    float b0 = 0, b1 = 0, b2 = 0, b3 = 0;                                    \
    _Pragma("unroll") for (int q = 6; q < 12; ++q) {                         \
      uint4 a = A4[q];                                                       \
      b0 = fmaf(__uint_as_float(a.x << 16), RR[8 * q + 0], b0);              \
      b1 = fmaf(__uint_as_float(a.x & 0xFFFF0000u), RR[8 * q + 1], b1);      \
      b2 = fmaf(__uint_as_float(a.y << 16), RR[8 * q + 2], b2);              \
      b3 = fmaf(__uint_as_float(a.y & 0xFFFF0000u), RR[8 * q + 3], b3);      \
      b0 = fmaf(__uint_as_float(a.z << 16), RR[8 * q + 4], b0);              \
      b1 = fmaf(__uint_as_float(a.z & 0xFFFF0000u), RR[8 * q + 5], b1);      \
      b2 = fmaf(__uint_as_float(a.w << 16), RR[8 * q + 6], b2);              \
      b3 = fmaf(__uint_as_float(a.w & 0xFFFF0000u), RR[8 * q + 7], b3);      \
    }                                                                        \
    SHI = (b0 + b1) + (b2 + b3);                                             \
  }

__global__ void init_ws(u64* ws) {
  const size_t n1 = (size_t)4 * Tn * Ln;
  const size_t n = n1 * 9;  // axp + 8 chains
  for (size_t i = (size_t)blockIdx.x * blockDim.x + threadIdx.x; i < n;
       i += (size_t)gridDim.x * blockDim.x)
    ws[i] = (i < n1) ? (((u64)SENT) << 32) : 0ull;
}

__global__ __launch_bounds__(512, 1) void semicrf(
    const float* __restrict__ seg, const float* __restrict__ tr,
    float* __restrict__ out, u64* axp, u64* acc) {
  const int b = blockIdx.x / NROLE;
  const int role = blockIdx.x % NROLE;
  const int tid = threadIdx.x;

  __shared__ __align__(16) float E[LSQ];           // exp(trans) 36 KB
  __shared__ __align__(16) u16 AlbRh[8][Ln];       // bf16 alpha ring
  __shared__ float CRng[8][2];                     // per-half C ring
  __shared__ __align__(16) float slotC2[4][Ln];    // d2 contributions
  __shared__ __align__(16) float slotC3[4][Ln];    // d3 contributions
  __shared__ float RESTm[4][Ln];                   // chains+z merge (m)
  __shared__ float RESTv[4][Ln];                   // chains+z merge (v)
  __shared__ __align__(16) float Alb_s[4][2][Ln];  // relay staging (dbuf)
  __shared__ float CstS[4][2][2];
  __shared__ float redbuf[2];
  __shared__ int stg[4][2];

  if (tid < 8) stg[tid >> 1][tid & 1] = -1;
  for (int i = tid; i < LSQ; i += 512) E[i] = __expf(tr[i]);
  __syncthreads();  // init barrier (all blocks)

  if (role != 0) {
    // == relay pair-unit: pu=(role-1)*4+pair -> d=4+pu/3, split m=pu%3 =======
    const int pair = tid >> 7;
    const int tp = tid & 127;
    const int wv = tp >> 6;
    const int rl = tp & 63;
    const bool act = rl < HL;
    const int lab = wv * HL + (act ? rl : HL - 1);
    const int pu = (role - 1) * 4 + pair;  // 0..179
    const int d = 4 + pu / 3;
    const int m3 = pu % 3;
    const int j = d & 7;
    u64* chain = acc + (size_t)(j * 4 + b) * Tn * Ln;
    const u64* axB = axp + (size_t)b * Tn * Ln;
    float R[Ln];
#pragma unroll
    for (int lp = 0; lp < Ln; ++lp) R[lp] = E[lp * Ln + lab];
    int wc = 1;
    const bool aHead = (d + KCH > Wn);
    const int t0 = d + ((m3 - (d % 3)) + 3) % 3;
    int bufi = 0;

    for (int t = t0; t < Tn; t += 3) {
      const int s = t - d;
      const int w = (t <= Wn) ? (s + 1) : (64 - d);
      while (w > wc) {
        ++wc;
#pragma unroll
        for (int lp = 0; lp < Ln; ++lp) R[lp] *= E[lp * Ln + lab];
      }
      const float segv = seg[SIDX(b, s + 1, t) + lab];
      const size_t tIdx = (size_t)t * Ln + lab;
      const bool head = aHead || (s < KCH);
      u64 ua = 0;
      if (!head) ua = __hip_atomic_load(&chain[tIdx], RLX, AGENT);

      u64 up = __hip_atomic_load(&axB[(size_t)s * Ln + lab], RLX, AGENT);
      while ((u32)(up >> 32) == SENT)
        up = __hip_atomic_load(&axB[(size_t)s * Ln + lab], RLX, AGENT);

      if (act) Alb_s[pair][bufi][lab] = __uint_as_float((u32)up);
      if (rl == 0) CstS[pair][bufi][wv] = __uint_as_float((u32)(up >> 32));
      LDSF();
      __hip_atomic_store(&stg[pair][wv], t, RLX, WG);
      while (__hip_atomic_load(&stg[pair][wv ^ 1], RLX, WG) < t) {}
      CBAR();
      const float C0 = CstS[pair][bufi][0], C1 = CstS[pair][bufi][1];
      MV1(Alb_s[pair][bufi], R, Slo, Shi)
      const float c = comb(Slo, Shi, C0, C1, (float)w * segv);
      bufi ^= 1;

      float m, v;
      if (head) {
        m = c;
        v = 1.f;
      } else {
        while (((ua >> 32) & 0xFFu) != (u32)(d + KCH))
          ua = __hip_atomic_load(&chain[tIdx], RLX, AGENT);
        const float pm = __uint_as_float((u32)ua);
        const float pv = __uint_as_float(((u32)(ua >> 32)) & ~0xFFu);
        const float nm = fmaxf(pm, c);
        v = pv * __expf(pm - nm) + __expf(c - nm);
        m = nm;
      }
      if (act) {
        const u32 vb = (__float_as_uint(v) & ~0xFFu) | (u32)d;
        __hip_atomic_store(&chain[tIdx],
                           (u64)__float_as_uint(m) | ((u64)vb << 32), RLX,
                           AGENT);
      }
    }
    return;
  }

  // ================== finalizer block: barrier lockstep ====================
  const int w6 = tid >> 6;
  const int l = tid & 63;
  const bool act = l < HL;
  const int h = w6 & 1;
  const int lab = h * HL + (act ? l : HL - 1);
  u64* axpB = axp + (size_t)b * Tn * Ln;
  const float bos = tr[LSQ + lab];

  if (w6 < 2) {
    // ------------------------------ CORE -----------------------------------
    float R1[Ln];
#pragma unroll
    for (int lp = 0; lp < Ln; ++lp) R1[lp] = E[lp * Ln + lab];
    int w1c = 1;
    float q0 = seg[SIDX(b, 1, 1) + lab];
    float q1 = seg[SIDX(b, 2, 2) + lab];
    // seed t=0: alpha0 = exp(seg[b,0,0,:]+bos) (reference stores exp'd value)
    {
      const float a0 = __expf(seg[SIDX(b, 0, 0) + lab] + bos);
      const float Cw = wavemax48(act ? a0 : NEGINF);
      const float ax0 = __expf(a0 - Cw);
      if (act) __hip_atomic_store(&axpB[lab], pack2(ax0, Cw), RLX, AGENT);
      if (act) AlbRh[0][lab] = tobf16(ax0);
      if (l == 0) CRng[0][h] = Cw;
    }
    BARRIER();

    float lastAx = 0.f, lastCw = 0.f;
    for (int t = 1; t < Tn; ++t) {
      const float s1 = q0;
      q0 = q1;
      if (t + 2 < Tn) q1 = seg[SIDX(b, t + 2, t + 2) + lab];
      const int w1 = (t <= Wn) ? t : Wn;
      if (w1 > w1c) {
        w1c = w1;
#pragma unroll
        for (int lp = 0; lp < Ln; ++lp) R1[lp] *= E[lp * Ln + lab];
      }
      const float C0 = CRng[(t - 1) & 7][0], C1 = CRng[(t - 1) & 7][1];
      MVB(AlbRh[(t - 1) & 7], R1, Slo, Shi)
      const float c1 = comb(Slo, Shi, C0, C1, (float)w1 * s1);
      const float c2 = (t >= 2) ? slotC2[t & 3][lab] : NEGINF;
      const float c3 = (t >= 3) ? slotC3[t & 3][lab] : NEGINF;
      const float mr = RESTm[t & 3][lab], vr = RESTv[t & 3][lab];
      const float M = fmaxf(fmaxf(c1, c2), fmaxf(c3, mr));
      const float vs = __expf(c1 - M) + __expf(c2 - M) + __expf(c3 - M) +
                       vr * __expf(mr - M);
      const float alpha = M + __logf(vs);
      const float Cw = wavemax48(act ? alpha : NEGINF);
      const float axn = __expf(alpha - Cw);
      if (act)
        __hip_atomic_store(&axpB[(size_t)t * Ln + lab], pack2(axn, Cw), RLX,
                           AGENT);
      if (act) AlbRh[t & 7][lab] = tobf16(axn);
      if (l == 0) CRng[t & 7][h] = Cw;
      lastAx = axn;
      lastCw = Cw;
      BARRIER();
    }
    const float sm = wsumred(act ? lastAx : 0.f);
    if (l == 0) redbuf[h] = lastCw + __logf(sm);
    BARRIER();
    if (w6 == 0 && l == 0) {
      const float G0 = redbuf[0], G1 = redbuf[1];
      const float Mx = fmaxf(G0, G1);
      out[b] = Mx + __logf(__expf(G0 - Mx) + __expf(G1 - Mx));
    }
    return;
  }

  if (w6 < 4) {
    // ------------------------------ d2 -------------------------------------
    float R2[Ln];
#pragma unroll
    for (int lp = 0; lp < Ln; ++lp) R2[lp] = E[lp * Ln + lab];
    int wc = 1;
    float q0 = seg[SIDX(b, 1, 2) + lab];  // tp1=2
    float q1 = seg[SIDX(b, 2, 3) + lab];  // tp1=3
    BARRIER();
    for (int t = 1; t < Tn; ++t) {
      const int tp1 = t + 1;
      if (tp1 < Tn) {
        const float sv = q0;
        q0 = q1;
        if (tp1 + 2 < Tn) q1 = seg[SIDX(b, tp1 + 1, tp1 + 2) + lab];
        const int w = (tp1 <= Wn) ? (tp1 - 1) : 62;
        if (w > wc) {
          wc = w;
#pragma unroll
          for (int lp = 0; lp < Ln; ++lp) R2[lp] *= E[lp * Ln + lab];
        }
        const float C0 = CRng[(t - 1) & 7][0], C1 = CRng[(t - 1) & 7][1];
        MVB(AlbRh[(t - 1) & 7], R2, Slo, Shi)
        const float c = comb(Slo, Shi, C0, C1, (float)w * sv);
        if (act) slotC2[tp1 & 3][lab] = c;
      }
      BARRIER();
    }
    BARRIER();
    return;
  }

  if (w6 < 6) {
    // ------------------------------ d3 -------------------------------------
    float R3[Ln];
#pragma unroll
    for (int lp = 0; lp < Ln; ++lp) R3[lp] = E[lp * Ln + lab];
    int wc = 1;
    float q0 = 0.f;                       // tp1=2 (unused)
    float q1 = seg[SIDX(b, 1, 3) + lab];  // tp1=3
    BARRIER();
    for (int t = 1; t < Tn; ++t) {
      const int tp1 = t + 1;
      if (tp1 < Tn) {
        const float sv = q0;
        q0 = q1;
        if (tp1 + 2 < Tn) q1 = seg[SIDX(b, tp1, tp1 + 2) + lab];
        if (tp1 >= 3) {
          const int w = (tp1 <= Wn) ? (tp1 - 2) : 61;
          if (w > wc) {
            wc = w;
#pragma unroll
            for (int lp = 0; lp < Ln; ++lp) R3[lp] *= E[lp * Ln + lab];
          }
          const float C0 = CRng[(t - 2) & 7][0], C1 = CRng[(t - 2) & 7][1];
          MVB(AlbRh[(t - 2) & 7], R3, Slo, Shi)
          const float c = comb(Slo, Shi, C0, C1, (float)w * sv);
          if (act) slotC3[tp1 & 3][lab] = c;
        }
      }
      BARRIER();
    }
    BARRIER();
    return;
  }

  {
    // ------------------------------ REST ------------------------------------
    const int endd[8] = {8, 9, 10, 11, 4, 5, 6, 7};
    u64 UA[8], UB[8];
#pragma unroll
    for (int jj = 0; jj < 8; ++jj) {
      UA[jj] = 0;
      UB[jj] = 0;
    }
    float zq0 = seg[SIDX(b, 0, 2) + lab];  // z(2)
    float zq1 = seg[SIDX(b, 0, 3) + lab];  // z(3)
    // seed: REST(1) = z(1) only
    {
      const float zv = 2.f * (seg[SIDX(b, 0, 1) + lab] + bos);
      if (act) {
        RESTm[1][lab] = zv;
        RESTv[1][lab] = 1.f;
      }
    }
    BARRIER();

#define RESTSTEP(U)                                                          \
  {                                                                          \
    float M = zv;                                                            \
    float em[8], ev[8];                                                      \
    _Pragma("unroll") for (int jj = 0; jj < 8; ++jj) {                       \
      if (tp1 >= endd[jj]) {                                                 \
        const size_t aIdx = (((size_t)jj * 4 + b) * Tn + tp1) * Ln + lab;    \
        while (((U[jj] >> 32) & 0xFFu) != (u32)endd[jj])                     \
          U[jj] = __hip_atomic_load(&acc[aIdx], RLX, AGENT);                 \
        em[jj] = __uint_as_float((u32)U[jj]);                                \
        ev[jj] = __uint_as_float(((u32)(U[jj] >> 32)) & ~0xFFu);             \
        M = fmaxf(M, em[jj]);                                                \
      } else {                                                               \
        em[jj] = NEGINF;                                                     \
        ev[jj] = 0.f;                                                        \
      }                                                                      \
    }                                                                        \
    float vs = __expf(zv - M);                                               \
    _Pragma("unroll") for (int jj = 0; jj < 8; ++jj) vs +=                   \
        ev[jj] * __expf(em[jj] - M);                                         \
    if (act) {                                                               \
      RESTm[tp1 & 3][lab] = M;                                               \
      RESTv[tp1 & 3][lab] = vs;                                              \
    }                                                                        \
    if (tp1 + 2 < Tn) {                                                      \
      _Pragma("unroll") for (int jj = 0; jj < 8; ++jj) {                     \
        if (tp1 + 2 >= endd[jj])                                             \
          U[jj] = __hip_atomic_load(                                         \
              &acc[(((size_t)jj * 4 + b) * Tn + (tp1 + 2)) * Ln + lab], RLX, \
              AGENT);                                                        \
      }                                                                      \
    }                                                                        \
  }

    for (int t = 1; t < Tn; ++t) {
      const int tp1 = t + 1;
      if (tp1 < Tn) {
        const float zv =
            (tp1 <= Wn) ? (float)(tp1 + 1) * (zq0 + bos) : NEGINF;
        zq0 = zq1;
        if (tp1 + 2 <= Wn) zq1 = seg[SIDX(b, 0, tp1 + 2) + lab];
        if (tp1 & 1) {
          RESTSTEP(UA)
        } else {
          RESTSTEP(UB)
        }
      }
      BARRIER();
    }
    BARRIER();
    return;
  }
}

extern "C" void kernel_launch(void* const* d_in, const int* in_sizes, int n_in,
                              void* d_out, int out_size, void* d_ws,
                              size_t ws_size, hipStream_t stream) {
  const float* seg = (const float*)d_in[0];  // (4,512,512,96) f32
  const float* tr = (const float*)d_in[1];   // (97,96) f32
  float* out = (float*)d_out;                // (4,) f32

  u64* axp = (u64*)d_ws;                 // [4][512][96]
  u64* acc = axp + (size_t)4 * Tn * Ln;  // [8][4][512][96]

  hipLaunchKernelGGL(init_ws, dim3(2048), dim3(256), 0, stream, (u64*)d_ws);
  hipLaunchKernelGGL(semicrf, dim3(4 * NROLE), dim3(512), 0, stream, seg, tr,
                     out, axp, acc);
}